// Round 1
// baseline (1861.229 us; speedup 1.0000x reference)
//
#include <hip/hip_runtime.h>

#define B_ 2
#define S_ 2048
#define D_ 1024
#define H_ 16
#define DEPTH_ 64

// XOR-swizzled float4-group index for transposed 64x64 LDS tiles (stride 64,
// 16B-aligned rows, conflict-free b128 reads AND scatter stores).
#define SWZ(g, d) ((((g) ^ ((d) & 15)) << 2))

typedef float f4v __attribute__((ext_vector_type(4)));

// ---------------------------------------------------------------------------
// gemm128 body: C(4096x1024) = A(4096x1024) @ B(1024x1024) + bias.
// Tile 128x128x16, 256 threads, 8x8 accumulators/thread.
// ---------------------------------------------------------------------------
__device__ __forceinline__ void gemm128_body(
    const float* __restrict__ A, const float* __restrict__ Bw,
    const float* __restrict__ bias, float* __restrict__ C)
{
    __shared__ float As[16][132];   // [k][row]
    __shared__ float Bs[16][132];   // [k][col]
    int t = threadIdx.x;
    int row0 = blockIdx.y * 128, col0 = blockIdx.x * 128;

    int ar = t >> 2, ak = (t & 3) << 2;    // A rows ar, ar+64; k offs ak..ak+3
    int bk = t >> 5, bc = (t & 31) << 2;   // B k rows bk, bk+8; cols bc..bc+3
    int tm = (t >> 4) << 3, tn = (t & 15) << 3;

    float acc[8][8] = {};

    for (int k0 = 0; k0 < 1024; k0 += 16) {
        float4 a0 = *(const float4*)(A + (long)(row0 + ar) * 1024 + k0 + ak);
        float4 a1 = *(const float4*)(A + (long)(row0 + ar + 64) * 1024 + k0 + ak);
        float4 b0 = *(const float4*)(Bw + (long)(k0 + bk) * 1024 + col0 + bc);
        float4 b1 = *(const float4*)(Bw + (long)(k0 + bk + 8) * 1024 + col0 + bc);
        As[ak + 0][ar] = a0.x; As[ak + 1][ar] = a0.y;
        As[ak + 2][ar] = a0.z; As[ak + 3][ar] = a0.w;
        As[ak + 0][ar + 64] = a1.x; As[ak + 1][ar + 64] = a1.y;
        As[ak + 2][ar + 64] = a1.z; As[ak + 3][ar + 64] = a1.w;
        *(float4*)&Bs[bk][bc] = b0;
        *(float4*)&Bs[bk + 8][bc] = b1;
        __syncthreads();
#pragma unroll
        for (int kk = 0; kk < 16; ++kk) {
            float4 x0 = *(const float4*)&As[kk][tm];
            float4 x1 = *(const float4*)&As[kk][tm + 4];
            float4 y0 = *(const float4*)&Bs[kk][tn];
            float4 y1 = *(const float4*)&Bs[kk][tn + 4];
            float xa[8] = {x0.x, x0.y, x0.z, x0.w, x1.x, x1.y, x1.z, x1.w};
            float yb[8] = {y0.x, y0.y, y0.z, y0.w, y1.x, y1.y, y1.z, y1.w};
#pragma unroll
            for (int i = 0; i < 8; ++i)
#pragma unroll
                for (int j = 0; j < 8; ++j) acc[i][j] += xa[i] * yb[j];
        }
        __syncthreads();
    }

    float4 bv0 = *(const float4*)(bias + col0 + tn);
    float4 bv1 = *(const float4*)(bias + col0 + tn + 4);
#pragma unroll
    for (int i = 0; i < 8; ++i) {
        float4 o0, o1;
        o0.x = acc[i][0] + bv0.x; o0.y = acc[i][1] + bv0.y;
        o0.z = acc[i][2] + bv0.z; o0.w = acc[i][3] + bv0.w;
        o1.x = acc[i][4] + bv1.x; o1.y = acc[i][5] + bv1.y;
        o1.z = acc[i][6] + bv1.z; o1.w = acc[i][7] + bv1.w;
        float* cp = C + (long)(row0 + tm + i) * 1024 + col0;
        *(float4*)(cp + tn) = o0;
        *(float4*)(cp + tn + 4) = o1;
    }
}

__global__ __launch_bounds__(256, 2) void gemm128(
    const float* __restrict__ A, const float* __restrict__ Bw,
    const float* __restrict__ bias, float* __restrict__ C)
{
    gemm128_body(A, Bw, bias, C);
}

// Q,K,V projections batched in one launch: gridDim.z selects the weight set.
// 768 blocks -> 2 resident blocks/CU so barrier drains overlap with compute.
__global__ __launch_bounds__(256, 2) void gemm128_qkv(
    const float* __restrict__ x,
    const float* __restrict__ Wq, const float* __restrict__ bq,
    const float* __restrict__ Wk, const float* __restrict__ bk,
    const float* __restrict__ Wv, const float* __restrict__ bv,
    float* __restrict__ q, float* __restrict__ k, float* __restrict__ v)
{
    const float* Bw; const float* bias; float* C;
    if (blockIdx.z == 0)      { Bw = Wq; bias = bq; C = q; }
    else if (blockIdx.z == 1) { Bw = Wk; bias = bk; C = k; }
    else                      { Bw = Wv; bias = bv; C = v; }
    gemm128_body(x, Bw, bias, C);
}

// ---------------------------------------------------------------------------
// attn_fused: scores + softmax + attn@V in ONE kernel, attn written once.
// Block = 64 q-rows of one (b,h). Pass A sweeps K computing per-row max and
// sumexp entirely in registers (16-lane shfl reductions, K double-buffered,
// 1 barrier/tile). Pass B recomputes QK^T, normalizes, streams attn out
// (non-temporal), and accumulates attn@V. Eliminates the 512 MB logits write
// and both 512 MB logits reads of the old scores/attn_av pair.
// ---------------------------------------------------------------------------
__global__ __launch_bounds__(256, 2) void attn_fused(
    const float* __restrict__ q, const float* __restrict__ k,
    const float* __restrict__ v, const float* __restrict__ mask,
    float* __restrict__ attn, float* __restrict__ z)
{
    __shared__ float Qs[64 * 64];   // [d][qrow] swizzled (whole kernel)
    __shared__ float Ka[64 * 64];   // pass A: K dbuf 0; pass B: K tile
    __shared__ float Kb[64 * 64];   // pass A: K dbuf 1; pass B: Ps (attn tile)
    __shared__ float Vs[64 * 64];   // [key][d] direct (pass B)

    int t = threadIdx.x;
    // XCD-chunked block swizzle: 1024 blocks % 8 XCDs == 0 -> bijective.
    // Clusters all q-tiles of ~4 consecutive (b,h) on one XCD so K/V tiles
    // (1 MB per bh) stay L2-resident across the 32 q-blocks that share them.
    int bid = blockIdx.y * 32 + blockIdx.x;
    bid = (bid & 7) * 128 + (bid >> 3);
    int q0 = (bid & 31) * 64;
    int bh = bid >> 5, b = bh >> 4, h = bh & 15;

    int rr = t >> 4, c4 = (t & 15) << 2;
    int tm = rr << 2, tn = c4;          // 4 q-rows tm..tm+3, 4 keys tn..tn+3
    int gm = rr, gn = t & 15;

    const float* qb = q + (long)(b * S_ + q0) * D_ + h * DEPTH_;
    const float* kb0 = k + ((long)b * S_) * D_ + h * DEPTH_;
    const float* vb0 = v + ((long)b * S_) * D_ + h * DEPTH_;

    // Q tile -> LDS (transposed + swizzled), resident for both passes.
#pragma unroll
    for (int i = 0; i < 4; ++i) {
        int r = rr + 16 * i;
        float4 qv = *(const float4*)(qb + (long)r * D_ + c4);
        int g = r >> 2, e = r & 3;
        Qs[(c4 + 0) * 64 + SWZ(g, c4 + 0) + e] = qv.x;
        Qs[(c4 + 1) * 64 + SWZ(g, c4 + 1) + e] = qv.y;
        Qs[(c4 + 2) * 64 + SWZ(g, c4 + 2) + e] = qv.z;
        Qs[(c4 + 3) * 64 + SWZ(g, c4 + 3) + e] = qv.w;
    }

    float mq[4];
#pragma unroll
    for (int i = 0; i < 4; ++i) mq[i] = mask[b * S_ + q0 + tm + i];

    // ---------------- pass A: per-row running max & sumexp -----------------
    float m_run[4] = {-1e30f, -1e30f, -1e30f, -1e30f};
    float l_run[4] = {0.f, 0.f, 0.f, 0.f};

    float4 kreg[4], vreg[4];
#pragma unroll
    for (int i = 0; i < 4; ++i)
        kreg[i] = *(const float4*)(kb0 + (long)(rr + 16 * i) * D_ + c4);
#pragma unroll
    for (int i = 0; i < 4; ++i) {
        int r = rr + 16 * i, g = r >> 2, e = r & 3;
        Ka[(c4 + 0) * 64 + SWZ(g, c4 + 0) + e] = kreg[i].x;
        Ka[(c4 + 1) * 64 + SWZ(g, c4 + 1) + e] = kreg[i].y;
        Ka[(c4 + 2) * 64 + SWZ(g, c4 + 2) + e] = kreg[i].z;
        Ka[(c4 + 3) * 64 + SWZ(g, c4 + 3) + e] = kreg[i].w;
    }

    for (int kt = 0; kt < 32; ++kt) {
        __syncthreads();                      // buffer for tile kt ready
        if (kt < 31) {                        // issue next-tile loads early
            const float* kp = kb0 + (long)(kt + 1) * 64 * D_;
#pragma unroll
            for (int i = 0; i < 4; ++i)
                kreg[i] = *(const float4*)(kp + (long)(rr + 16 * i) * D_ + c4);
        }
        const float* KT = (kt & 1) ? Kb : Ka;
        float acc[4][4] = {};
#pragma unroll
        for (int kk = 0; kk < 64; ++kk) {
            float4 qa = *(const float4*)&Qs[kk * 64 + SWZ(gm, kk)];
            float4 kv = *(const float4*)&KT[kk * 64 + SWZ(gn, kk)];
            float xa[4] = {qa.x, qa.y, qa.z, qa.w};
            float yb[4] = {kv.x, kv.y, kv.z, kv.w};
#pragma unroll
            for (int i = 0; i < 4; ++i)
#pragma unroll
                for (int j = 0; j < 4; ++j) acc[i][j] += xa[i] * yb[j];
        }
        float4 mk4 = *(const float4*)(mask + b * S_ + kt * 64 + tn);
        float mk[4] = {mk4.x, mk4.y, mk4.z, mk4.w};
#pragma unroll
        for (int i = 0; i < 4; ++i) {
            float lg[4];
#pragma unroll
            for (int j = 0; j < 4; ++j)
                lg[j] = acc[i][j] * 0.125f + fminf(1.0f, mq[i] + mk[j]);
            float tmax = fmaxf(fmaxf(lg[0], lg[1]), fmaxf(lg[2], lg[3]));
#pragma unroll
            for (int off = 8; off; off >>= 1)
                tmax = fmaxf(tmax, __shfl_xor(tmax, off, 64));
            float s = __expf(lg[0] - tmax) + __expf(lg[1] - tmax) +
                      __expf(lg[2] - tmax) + __expf(lg[3] - tmax);
#pragma unroll
            for (int off = 8; off; off >>= 1) s += __shfl_xor(s, off, 64);
            float mnew = fmaxf(m_run[i], tmax);
            l_run[i] = l_run[i] * __expf(m_run[i] - mnew) + s * __expf(tmax - mnew);
            m_run[i] = mnew;
        }
        if (kt < 31) {                        // write next tile to other buf
            float* KT2 = (kt & 1) ? Ka : Kb;
#pragma unroll
            for (int i = 0; i < 4; ++i) {
                int r = rr + 16 * i, g = r >> 2, e = r & 3;
                KT2[(c4 + 0) * 64 + SWZ(g, c4 + 0) + e] = kreg[i].x;
                KT2[(c4 + 1) * 64 + SWZ(g, c4 + 1) + e] = kreg[i].y;
                KT2[(c4 + 2) * 64 + SWZ(g, c4 + 2) + e] = kreg[i].z;
                KT2[(c4 + 3) * 64 + SWZ(g, c4 + 3) + e] = kreg[i].w;
            }
        }
    }

    float linv[4];
#pragma unroll
    for (int i = 0; i < 4; ++i) linv[i] = 1.0f / l_run[i];

    // ---------------- pass B: normalize + write attn, accumulate @V --------
    float* arow = attn + (long)bh * S_ * S_;
    float zacc[4][4] = {};

#pragma unroll
    for (int i = 0; i < 4; ++i) {
        kreg[i] = *(const float4*)(kb0 + (long)(rr + 16 * i) * D_ + c4);
        vreg[i] = *(const float4*)(vb0 + (long)(rr + 16 * i) * D_ + c4);
    }

    for (int kt = 0; kt < 32; ++kt) {
        // stage K -> Ka (swizzled), V -> Vs (direct); regs from prev iter
#pragma unroll
        for (int i = 0; i < 4; ++i) {
            int r = rr + 16 * i, g = r >> 2, e = r & 3;
            Ka[(c4 + 0) * 64 + SWZ(g, c4 + 0) + e] = kreg[i].x;
            Ka[(c4 + 1) * 64 + SWZ(g, c4 + 1) + e] = kreg[i].y;
            Ka[(c4 + 2) * 64 + SWZ(g, c4 + 2) + e] = kreg[i].z;
            Ka[(c4 + 3) * 64 + SWZ(g, c4 + 3) + e] = kreg[i].w;
            *(float4*)&Vs[r * 64 + c4] = vreg[i];
        }
        __syncthreads();                      // A: Ka, Vs ready
        if (kt < 31) {                        // issue next-tile loads early
            const float* kp = kb0 + (long)(kt + 1) * 64 * D_;
            const float* vp = vb0 + (long)(kt + 1) * 64 * D_;
#pragma unroll
            for (int i = 0; i < 4; ++i) {
                kreg[i] = *(const float4*)(kp + (long)(rr + 16 * i) * D_ + c4);
                vreg[i] = *(const float4*)(vp + (long)(rr + 16 * i) * D_ + c4);
            }
        }
        float acc[4][4] = {};
#pragma unroll
        for (int kk = 0; kk < 64; ++kk) {
            float4 qa = *(const float4*)&Qs[kk * 64 + SWZ(gm, kk)];
            float4 kv = *(const float4*)&Ka[kk * 64 + SWZ(gn, kk)];
            float xa[4] = {qa.x, qa.y, qa.z, qa.w};
            float yb[4] = {kv.x, kv.y, kv.z, kv.w};
#pragma unroll
            for (int i = 0; i < 4; ++i)
#pragma unroll
                for (int j = 0; j < 4; ++j) acc[i][j] += xa[i] * yb[j];
        }
        float4 mk4 = *(const float4*)(mask + b * S_ + kt * 64 + tn);
#pragma unroll
        for (int i = 0; i < 4; ++i) {
            float4 o;
            o.x = __expf(acc[i][0] * 0.125f + fminf(1.0f, mq[i] + mk4.x) - m_run[i]) * linv[i];
            o.y = __expf(acc[i][1] * 0.125f + fminf(1.0f, mq[i] + mk4.y) - m_run[i]) * linv[i];
            o.z = __expf(acc[i][2] * 0.125f + fminf(1.0f, mq[i] + mk4.z) - m_run[i]) * linv[i];
            o.w = __expf(acc[i][3] * 0.125f + fminf(1.0f, mq[i] + mk4.w) - m_run[i]) * linv[i];
            // streaming attn write, never re-read -> non-temporal (spare L2)
            f4v ov = {o.x, o.y, o.z, o.w};
            __builtin_nontemporal_store(
                ov, (f4v*)(arow + (long)(q0 + tm + i) * S_ + kt * 64 + tn));
            // scatter P into Kb (=Ps) [key][qrow] swizzled for the AV pass
            Kb[(tn + 0) * 64 + SWZ(gm, tn + 0) + i] = o.x;
            Kb[(tn + 1) * 64 + SWZ(gm, tn + 1) + i] = o.y;
            Kb[(tn + 2) * 64 + SWZ(gm, tn + 2) + i] = o.z;
            Kb[(tn + 3) * 64 + SWZ(gm, tn + 3) + i] = o.w;
        }
        __syncthreads();                      // B: Ps ready
#pragma unroll
        for (int kk = 0; kk < 64; ++kk) {
            float4 pa = *(const float4*)&Kb[kk * 64 + SWZ(gm, kk)];
            float4 vb = *(const float4*)&Vs[kk * 64 + tn];
            float xa[4] = {pa.x, pa.y, pa.z, pa.w};
            float yb[4] = {vb.x, vb.y, vb.z, vb.w};
#pragma unroll
            for (int i = 0; i < 4; ++i)
#pragma unroll
                for (int j = 0; j < 4; ++j) zacc[i][j] += xa[i] * yb[j];
        }
        __syncthreads();                      // C: Ps/Vs consumed
    }

#pragma unroll
    for (int i = 0; i < 4; ++i) {
        float4 o;
        o.x = zacc[i][0]; o.y = zacc[i][1]; o.z = zacc[i][2]; o.w = zacc[i][3];
        *(float4*)(z + (long)(b * S_ + q0 + tm + i) * D_ + h * DEPTH_ + tn) = o;
    }
}

// ---------------------------------------------------------------------------
extern "C" void kernel_launch(void* const* d_in, const int* in_sizes, int n_in,
                              void* d_out, int out_size, void* d_ws, size_t ws_size,
                              hipStream_t stream)
{
    const float* x    = (const float*)d_in[0];
    const float* mask = (const float*)d_in[1];
    const float* Wq   = (const float*)d_in[2];
    const float* bq   = (const float*)d_in[3];
    const float* Wk   = (const float*)d_in[4];
    const float* bk   = (const float*)d_in[5];
    const float* Wv   = (const float*)d_in[6];
    const float* bv   = (const float*)d_in[7];
    const float* Wo   = (const float*)d_in[8];
    const float* bo   = (const float*)d_in[9];

    float* out  = (float*)d_out;                  // (B,S,D)
    float* attn = out + (size_t)B_ * S_ * D_;     // (B,H,S,S)

    size_t n = (size_t)B_ * S_ * D_;
    float* q = (float*)d_ws;
    float* k = q + n;
    float* v = k + n;
    float* z = v + n;

    dim3 blk(256);
    gemm128_qkv<<<dim3(8, 32, 3), blk, 0, stream>>>(x, Wq, bq, Wk, bk, Wv, bv,
                                                    q, k, v);
    attn_fused<<<dim3(32, 32), blk, 0, stream>>>(q, k, v, mask, attn, z);
    gemm128<<<dim3(8, 32), blk, 0, stream>>>(z, Wo, bo, out);
}